// Round 9
// baseline (154.363 us; speedup 1.0000x reference)
//
#include <hip/hip_runtime.h>
#include <stdint.h>
#include <math.h>

#define TPB   512    // 8 waves/block -> 4 blocks/CU at the 32-wave cap
#define KTOP  100
#define K1    128    // per-image selection rank cut
#define CAPS  768    // per-slice survivor region capacity (~450 expected max)
#define SR    8      // slice rows

#define HB 272
#define WB 480
#define NSB 34       // 272/8
#define HP 68
#define WP 120
#define NSP 9        // ceil(68/8), last slice 4 rows
#define NB 64

// ============================================================================
// Validated invariants (rounds 2-8, absmax 0.0):
//  - np-f32 softmax p is a MONOTONE function G of D = fl32(x1-x0).
//  - G-collapse window (rigorous): |dD| <= 2.4e-7 * e^max(D,0)
//    (ulp(p)/G'(D), both sign regimes). Threshold 4e-7*__expf(max(mx,0))
//    gives >= 1.6x margin incl. __expf's 2-ulp error.
//  - NMS: keep iff p >= all 8 neighbors; D-space fast path + exact G on ties.
//  - top-k tie order: (p desc, idx asc)  ==  u64 key (p_bits<<32 | ~idx) desc.
//  - 16-bit D-key rank-128 cut (ties included) contains the exact top-100 set.
// Round-7 lesson: no per-element global atomics. Round-8 lesson: no extra
// launches / counter-init kernels — write counts unconditionally.
// ============================================================================
__device__ __forceinline__ float G_exact(float D) {
    float t = -fabsf(D);
    float etf = (float)exp((double)t);       // correctly-rounded f32 exp
    return (D > 0.0f) ? __fdiv_rn(1.0f, __fadd_rn(etf, 1.0f))
                      : __fdiv_rn(etf, __fadd_rn(1.0f, etf));
}

__device__ __forceinline__ uint32_t flip_f32(float D) {
    uint32_t u = __float_as_uint(D);
    return (u & 0x80000000u) ? ~u : (u | 0x80000000u);
}

// In-place suffix-sum of 256 u32 bins: hist[i] <- sum_{j>=i} hist[j].
__device__ __forceinline__ void suffix_scan_256(uint32_t* hist) {
    if (threadIdx.x < 64) {
        int lane = threadIdx.x;
        uint32_t h0 = hist[4*lane+0], h1 = hist[4*lane+1];
        uint32_t h2 = hist[4*lane+2], h3 = hist[4*lane+3];
        uint32_t tot = h0 + h1 + h2 + h3;
        uint32_t run = tot;
        #pragma unroll
        for (int d = 1; d < 64; d <<= 1) {
            uint32_t o = __shfl_down(run, d, 64);
            if (lane + d < 64) run += o;
        }
        uint32_t ab = run - tot;
        hist[4*lane+3] = ab + h3;
        hist[4*lane+2] = ab + h3 + h2;
        hist[4*lane+1] = ab + h3 + h2 + h1;
        hist[4*lane+0] = ab + tot;
    }
    __syncthreads();
}

// Descending bitonic sort of 256 u64 keys; TPB may exceed 256 (guarded).
__device__ void bitonic_sort_256(uint64_t* keys) {
    for (int k = 2; k <= 256; k <<= 1) {
        for (int j = k >> 1; j > 0; j >>= 1) {
            int i = threadIdx.x;
            if (i < 256) {
                int ixj = i ^ j;
                if (ixj > i) {
                    uint64_t ka = keys[i], kb = keys[ixj];
                    bool sw = ((ka < kb) == ((i & k) == 0));
                    if (sw) { keys[i] = kb; keys[ixj] = ka; }
                }
            }
            __syncthreads();
        }
    }
}

// 6-wide row window [c4-1 .. c4+4] from the LDS D-tile (OOB -> -inf).
template<int W>
__device__ __forceinline__ void row6(const float* df, int row, int c4, float* a) {
    const float4 m = ((const float4*)df)[(row * W + c4) >> 2];
    a[1] = m.x; a[2] = m.y; a[3] = m.z; a[4] = m.w;
    a[0] = (c4 > 0)     ? df[row * W + c4 - 1] : -INFINITY;
    a[5] = (c4 + 4 < W) ? df[row * W + c4 + 4] : -INFINITY;
}

// ---- stage 1: D-tile NMS -> per-slice region (u32 recs) + count ------------
// Record: key16<<12 | lr<<9 | c   (lr<8, c<512, 28 bits total).
template<int H, int W>
__device__ __forceinline__ void stage1_impl(const float* __restrict__ x,
                                            int s, int b,
                                            uint32_t* __restrict__ cnt_out,
                                            uint32_t* __restrict__ region,
                                            float* df, uint32_t* surv)
{
    constexpr int W4 = W / 4;
    constexpr int tileRows = SR + 2;
    const int r0 = s * SR;
    const int rows = (H - r0 < SR) ? (H - r0) : SR;

    __shared__ int s_cnt;
    if (threadIdx.x == 0) s_cnt = 0;

    const float*  x0  = x + (size_t)b * 2 * H * W;
    const float*  x1  = x0 + (size_t)H * W;
    const float4* x0v = (const float4*)x0;
    const float4* x1v = (const float4*)x1;
    float4* dfv = (float4*)df;

    // D tile (rows r0-1 .. r0+SR), float4-vectorized; OOB rows -> -inf.
    constexpr int nt4 = tileRows * W4;
    for (int t = threadIdx.x; t < nt4; t += TPB) {
        int tr = t / W4, c4 = t - tr * W4;        // compile-time divisor
        int r = r0 - 1 + tr;
        float4 d4 = make_float4(-INFINITY, -INFINITY, -INFINITY, -INFINITY);
        if (r >= 0 && r < H) {
            float4 a = x0v[r * W4 + c4];
            float4 c = x1v[r * W4 + c4];
            d4.x = __fsub_rn(c.x, a.x);
            d4.y = __fsub_rn(c.y, a.y);
            d4.z = __fsub_rn(c.z, a.z);
            d4.w = __fsub_rn(c.w, a.w);
        }
        dfv[t] = d4;
    }
    __syncthreads();

    // NMS (4 cells/iter), separable column-max; survivors -> LDS.
    const int groups = rows * W4;
    for (int g = threadIdx.x; g < groups; g += TPB) {
        int lr = g / W4, c4 = (g - lr * W4) << 2; // compile-time divisor
        int tr = lr + 1;
        float ap[6], ac[6], an[6], cm[6];
        row6<W>(df, tr - 1, c4, ap);
        row6<W>(df, tr,     c4, ac);
        row6<W>(df, tr + 1, c4, an);
        #pragma unroll
        for (int i = 0; i < 6; ++i) cm[i] = fmaxf(fmaxf(ap[i], ac[i]), an[i]);
        #pragma unroll
        for (int j = 0; j < 4; ++j) {
            float v = ac[j + 1];
            float mx = fmaxf(fmaxf(cm[j], cm[j + 2]), fmaxf(ap[j + 1], an[j + 1]));
            bool keep;
            if (v >= mx) keep = true;
            else {
                // rigorous G-distinct threshold: window <= 2.4e-7*e^max(mx,0)
                float thr = 4e-7f * __expf(fmaxf(mx, 0.0f));
                keep = (mx - v < thr) ? (G_exact(v) == G_exact(mx)) : false;
            }
            if (keep) {
                uint32_t key16 = flip_f32(v) >> 16;
                int pos = atomicAdd(&s_cnt, 1);
                if (pos < CAPS)
                    surv[pos] = (key16 << 12) | ((uint32_t)lr << 9) | (uint32_t)(c4 + j);
            }
        }
    }
    __syncthreads();

    const int n = (s_cnt < CAPS) ? s_cnt : CAPS;
    if (threadIdx.x == 0) *cnt_out = (uint32_t)n;
    for (int t = threadIdx.x; t < n; t += TPB) region[t] = surv[t];
}

__global__ __launch_bounds__(TPB) void stage1(const float* __restrict__ bmap,
                                              const float* __restrict__ pmap,
                                              uint32_t* __restrict__ bcnt,
                                              uint32_t* __restrict__ pcnt,
                                              uint32_t* __restrict__ blist,
                                              uint32_t* __restrict__ plist)
{
    __shared__ float df[(SR + 2) * WB];           // 19200 B (max of both maps)
    __shared__ uint32_t surv[CAPS];               // 3072 B
    const int b = blockIdx.y;
    if (blockIdx.x < NSB) {
        int s = blockIdx.x;
        stage1_impl<HB, WB>(bmap, s, b, bcnt + (size_t)b * NSB + s,
                            blist + ((size_t)b * NSB + s) * CAPS, df, surv);
    } else {
        int s = blockIdx.x - NSB;
        stage1_impl<HP, WP>(pmap, s, b, pcnt + (size_t)b * NSP + s,
                            plist + ((size_t)b * NSP + s) * CAPS, df, surv);
    }
}

// ---- stage 2: per-image D16 radix-select -> exact-p rerank -> decode -------
template<int H, int W, int NS, bool BALL>
__device__ __forceinline__ void stage2_impl(const float* __restrict__ xmap,
                                            const float* __restrict__ pbbox,
                                            const uint32_t* __restrict__ cnt,
                                            const uint32_t* __restrict__ list,
                                            float* __restrict__ outp, int b,
                                            uint32_t* hist, uint64_t* outb)
{
    __shared__ int s_out;
    __shared__ uint32_t s_bin, s_ab, s_bin2, s_none;
    __shared__ uint32_t scnt[NS];
    if (threadIdx.x == 0) { s_out = 0; s_none = 0; }
    if (threadIdx.x < NS) scnt[threadIdx.x] = cnt[threadIdx.x];
    if (threadIdx.x < 256) hist[threadIdx.x] = 0;
    __syncthreads();

    // Pass A: level-1 histogram of key16 high byte.
    for (int s = 0; s < NS; ++s) {
        const uint32_t* lp = list + (size_t)s * CAPS;
        const int n = (int)scnt[s];
        for (int t = threadIdx.x; t < n; t += TPB)
            atomicAdd(&hist[lp[t] >> 20], 1u);
    }
    __syncthreads();
    suffix_scan_256(hist);
    if (threadIdx.x < 256) {
        uint32_t si = hist[threadIdx.x];
        uint32_t sn = (threadIdx.x < 255) ? hist[threadIdx.x + 1] : 0u;
        if (threadIdx.x == 0 && si < K1) s_none = 1;
        if (si >= K1 && sn < K1) { s_bin = threadIdx.x; s_ab = sn; }
    }
    __syncthreads();

    uint32_t T16 = 0;
    if (!s_none) {
        const uint32_t b3 = s_bin;
        const uint32_t k2 = K1 - s_ab;
        if (threadIdx.x < 256) hist[threadIdx.x] = 0;
        __syncthreads();
        // Pass B: level-2 histogram among keys whose high byte == b3.
        for (int s = 0; s < NS; ++s) {
            const uint32_t* lp = list + (size_t)s * CAPS;
            const int n = (int)scnt[s];
            for (int t = threadIdx.x; t < n; t += TPB) {
                uint32_t k16 = lp[t] >> 12;
                if ((k16 >> 8) == b3) atomicAdd(&hist[k16 & 255u], 1u);
            }
        }
        __syncthreads();
        suffix_scan_256(hist);
        if (threadIdx.x < 256) {
            uint32_t si = hist[threadIdx.x];
            uint32_t sn = (threadIdx.x < 255) ? hist[threadIdx.x + 1] : 0u;
            if (si >= k2 && sn < k2) s_bin2 = threadIdx.x;
        }
        __syncthreads();
        T16 = (b3 << 8) | s_bin2;
    }

    // Pass C: compact finalists (>= T16, ties included); exact np p here.
    const float* x0 = xmap + (size_t)b * 2 * H * W;
    const float* x1 = x0 + (size_t)H * W;
    if (threadIdx.x < 256) outb[threadIdx.x] = 0;
    __syncthreads();
    for (int s = 0; s < NS; ++s) {
        const uint32_t* lp = list + (size_t)s * CAPS;
        const int n = (int)scnt[s];
        for (int t = threadIdx.x; t < n; t += TPB) {
            uint32_t sv = lp[t];
            if ((sv >> 12) >= T16) {
                int pos = atomicAdd(&s_out, 1);
                if (pos < 256) {
                    int gidx = (s * SR + (int)((sv >> 9) & 7u)) * W + (int)(sv & 511u);
                    float D = __fsub_rn(x1[gidx], x0[gidx]);
                    float p = G_exact(D);
                    outb[pos] = ((uint64_t)__float_as_uint(p) << 32) | (uint32_t)(~gidx);
                }
            }
        }
    }
    __syncthreads();
    bitonic_sort_256(outb);

    // Decode top-100 (exact (p desc, idx asc) order).
    if (threadIdx.x < KTOP) {
        uint64_t k = outb[threadIdx.x];
        int id = (int)(~(uint32_t)k);
        float o0 = 0.f, o1 = 0.f, o2 = 0.f, o3 = 0.f, val = 0.f;
        if ((unsigned)id < (unsigned)(H * W)) {
            val = __uint_as_float((uint32_t)(k >> 32));
            int yy = id / W, xx = id - yy * W;             // compile-time divisor
            constexpr float ds = BALL ? 4.0f : 16.0f;
            float xc = (float)xx * ds + (ds - 1.0f) * 0.5f;
            float yc = (float)yy * ds + (ds - 1.0f) * 0.5f;
            float t0 = 0.f, t1 = 0.f;
            float t2 = BALL ? 40.0f : 0.0f, t3 = BALL ? 40.0f : 0.0f;
            if (!BALL) {
                const float* bb = pbbox + (size_t)b * 4 * H * W;
                constexpr float sx = (float)W * ds, sy = (float)H * ds;
                t0 = bb[id]             * sx;
                t1 = bb[id + H * W]     * sy;
                t2 = bb[id + 2 * H * W] * sx;
                t3 = bb[id + 3 * H * W] * sy;
            }
            float bx = xc + t0, by = yc + t1;
            o0 = bx - 0.5f * t2;
            o1 = by - 0.5f * t3;
            o2 = bx + 0.5f * t2;
            o3 = by + 0.5f * t3;
        }
        float* op = outp + (size_t)threadIdx.x * 5;
        op[0] = o0; op[1] = o1; op[2] = o2; op[3] = o3; op[4] = val;
    }
}

__global__ __launch_bounds__(TPB) void stage2(const float* __restrict__ bmap,
                                              const float* __restrict__ pmap,
                                              const float* __restrict__ pbbox,
                                              const uint32_t* __restrict__ bcnt,
                                              const uint32_t* __restrict__ pcnt,
                                              const uint32_t* __restrict__ blist,
                                              const uint32_t* __restrict__ plist,
                                              float* __restrict__ out)
{
    __shared__ uint32_t hist[256];
    __shared__ uint64_t outb[256];
    if (blockIdx.x < NB) {
        int b = blockIdx.x;
        stage2_impl<HB, WB, NSB, true>(bmap, nullptr,
            bcnt + (size_t)b * NSB, blist + (size_t)b * NSB * CAPS,
            out + (size_t)NB * KTOP * 5 + (size_t)b * KTOP * 5, b, hist, outb);
    } else {
        int b = blockIdx.x - NB;
        stage2_impl<HP, WP, NSP, false>(pmap, pbbox,
            pcnt + (size_t)b * NSP, plist + (size_t)b * NSP * CAPS,
            out + (size_t)b * KTOP * 5, b, hist, outb);
    }
}

// ---- launch -----------------------------------------------------------------
extern "C" void kernel_launch(void* const* d_in, const int* in_sizes, int n_in,
                              void* d_out, int out_size, void* d_ws, size_t ws_size,
                              hipStream_t stream) {
    const float* pmap  = (const float*)d_in[0];   // [64,2,68,120]
    const float* pbbox = (const float*)d_in[1];   // [64,4,68,120]
    const float* bmap  = (const float*)d_in[2];   // [64,2,272,480]
    float* out = (float*)d_out;                   // player [64,100,5] then ball

    uint32_t* bcnt  = (uint32_t*)d_ws;                        // 64*34 u32
    uint32_t* pcnt  = bcnt + (size_t)NB * NSB;                // 64*9 u32
    uint32_t* blist = pcnt + (size_t)NB * NSP;                // 64*34*768 u32
    uint32_t* plist = blist + (size_t)NB * NSB * CAPS;        // 64*9*768 u32
    // ws usage: ~8.5 MB; counts written unconditionally each call (no init).

    stage1<<<dim3(NSB + NSP, NB), TPB, 0, stream>>>(bmap, pmap, bcnt, pcnt,
                                                    blist, plist);
    stage2<<<2 * NB, TPB, 0, stream>>>(bmap, pmap, pbbox, bcnt, pcnt,
                                       blist, plist, out);
}

// Round 10
// 148.623 us; speedup vs baseline: 1.0386x; 1.0386x over previous
//
#include <hip/hip_runtime.h>
#include <stdint.h>
#include <math.h>

#define TPB   512    // 8 waves/block -> 4 blocks/CU at the 32-wave cap
#define KTOP  100
#define K1    128    // per-image selection rank cut
#define CAPS  768    // per-slice survivor region capacity (~450 expected max)
#define SR    8      // slice rows

#define HB 272
#define WB 480
#define NSB 34       // 272/8
#define HP 68
#define WP 120
#define NSP 9        // ceil(68/8), last slice 4 rows
#define NB 64

// ============================================================================
// Validated invariants (rounds 2-9, absmax 0.0):
//  - np-f32 softmax p is a MONOTONE function G of D = fl32(x1-x0).
//  - G-collapse window (rigorous): |dD| <= 2.4e-7 * e^max(D,0);
//    threshold 4e-7*__expf(max(mx,0)) gives >=1.6x margin incl. expf error.
//  - NMS: keep iff p >= all 8 neighbors; D-space fast path + exact G on ties.
//  - top-k tie order: (p desc, idx asc)  ==  u64 key (p_bits<<32 | ~idx) desc.
//  - 16-bit D-key rank-128 cut (ties included) contains the exact top-100 set.
//  - k16 = flip(D)>>16 >= 0x80 for any finite D  =>  k16==0 marks invalid.
// Lessons: r7 = no per-element global atomics on shared lines; r8 = no extra
// init launches; r9 = no latency-serialized small segments — flatten loops.
// ============================================================================
__device__ __forceinline__ float G_exact(float D) {
    float t = -fabsf(D);
    float etf = (float)exp((double)t);       // correctly-rounded f32 exp
    return (D > 0.0f) ? __fdiv_rn(1.0f, __fadd_rn(etf, 1.0f))
                      : __fdiv_rn(etf, __fadd_rn(1.0f, etf));
}

__device__ __forceinline__ uint32_t flip_f32(float D) {
    uint32_t u = __float_as_uint(D);
    return (u & 0x80000000u) ? ~u : (u | 0x80000000u);
}

// In-place suffix-sum of 256 u32 bins: hist[i] <- sum_{j>=i} hist[j].
__device__ __forceinline__ void suffix_scan_256(uint32_t* hist) {
    if (threadIdx.x < 64) {
        int lane = threadIdx.x;
        uint32_t h0 = hist[4*lane+0], h1 = hist[4*lane+1];
        uint32_t h2 = hist[4*lane+2], h3 = hist[4*lane+3];
        uint32_t tot = h0 + h1 + h2 + h3;
        uint32_t run = tot;
        #pragma unroll
        for (int d = 1; d < 64; d <<= 1) {
            uint32_t o = __shfl_down(run, d, 64);
            if (lane + d < 64) run += o;
        }
        uint32_t ab = run - tot;
        hist[4*lane+3] = ab + h3;
        hist[4*lane+2] = ab + h3 + h2;
        hist[4*lane+1] = ab + h3 + h2 + h1;
        hist[4*lane+0] = ab + tot;
    }
    __syncthreads();
}

// Descending bitonic sort of 256 u64 keys; TPB may exceed 256 (guarded).
__device__ void bitonic_sort_256(uint64_t* keys) {
    for (int k = 2; k <= 256; k <<= 1) {
        for (int j = k >> 1; j > 0; j >>= 1) {
            int i = threadIdx.x;
            if (i < 256) {
                int ixj = i ^ j;
                if (ixj > i) {
                    uint64_t ka = keys[i], kb = keys[ixj];
                    bool sw = ((ka < kb) == ((i & k) == 0));
                    if (sw) { keys[i] = kb; keys[ixj] = ka; }
                }
            }
            __syncthreads();
        }
    }
}

// 6-wide row window [c4-1 .. c4+4] from the LDS D-tile (OOB -> -inf).
template<int W>
__device__ __forceinline__ void row6(const float* df, int row, int c4, float* a) {
    const float4 m = ((const float4*)df)[(row * W + c4) >> 2];
    a[1] = m.x; a[2] = m.y; a[3] = m.z; a[4] = m.w;
    a[0] = (c4 > 0)     ? df[row * W + c4 - 1] : -INFINITY;
    a[5] = (c4 + 4 < W) ? df[row * W + c4 + 4] : -INFINITY;
}

// ---- stage 1: D-tile NMS -> per-slice region (u32 recs) + count ------------
// Record: key16<<12 | lr<<9 | c   (lr<8, c<512, 28 bits total).
template<int H, int W>
__device__ __forceinline__ void stage1_impl(const float* __restrict__ x,
                                            int s, int b,
                                            uint32_t* __restrict__ cnt_out,
                                            uint32_t* __restrict__ region,
                                            float* df, uint32_t* surv)
{
    constexpr int W4 = W / 4;
    constexpr int tileRows = SR + 2;
    const int r0 = s * SR;
    const int rows = (H - r0 < SR) ? (H - r0) : SR;

    __shared__ int s_cnt;
    if (threadIdx.x == 0) s_cnt = 0;

    const float*  x0  = x + (size_t)b * 2 * H * W;
    const float*  x1  = x0 + (size_t)H * W;
    const float4* x0v = (const float4*)x0;
    const float4* x1v = (const float4*)x1;
    float4* dfv = (float4*)df;

    // D tile (rows r0-1 .. r0+SR), float4-vectorized; OOB rows -> -inf.
    constexpr int nt4 = tileRows * W4;
    for (int t = threadIdx.x; t < nt4; t += TPB) {
        int tr = t / W4, c4 = t - tr * W4;        // compile-time divisor
        int r = r0 - 1 + tr;
        float4 d4 = make_float4(-INFINITY, -INFINITY, -INFINITY, -INFINITY);
        if (r >= 0 && r < H) {
            float4 a = x0v[r * W4 + c4];
            float4 c = x1v[r * W4 + c4];
            d4.x = __fsub_rn(c.x, a.x);
            d4.y = __fsub_rn(c.y, a.y);
            d4.z = __fsub_rn(c.z, a.z);
            d4.w = __fsub_rn(c.w, a.w);
        }
        dfv[t] = d4;
    }
    __syncthreads();

    // NMS (4 cells/iter), separable column-max; survivors -> LDS.
    const int groups = rows * W4;
    for (int g = threadIdx.x; g < groups; g += TPB) {
        int lr = g / W4, c4 = (g - lr * W4) << 2; // compile-time divisor
        int tr = lr + 1;
        float ap[6], ac[6], an[6], cm[6];
        row6<W>(df, tr - 1, c4, ap);
        row6<W>(df, tr,     c4, ac);
        row6<W>(df, tr + 1, c4, an);
        #pragma unroll
        for (int i = 0; i < 6; ++i) cm[i] = fmaxf(fmaxf(ap[i], ac[i]), an[i]);
        #pragma unroll
        for (int j = 0; j < 4; ++j) {
            float v = ac[j + 1];
            float mx = fmaxf(fmaxf(cm[j], cm[j + 2]), fmaxf(ap[j + 1], an[j + 1]));
            bool keep;
            if (v >= mx) keep = true;
            else {
                float thr = 4e-7f * __expf(fmaxf(mx, 0.0f));
                keep = (mx - v < thr) ? (G_exact(v) == G_exact(mx)) : false;
            }
            if (keep) {
                uint32_t key16 = flip_f32(v) >> 16;
                int pos = atomicAdd(&s_cnt, 1);
                if (pos < CAPS)
                    surv[pos] = (key16 << 12) | ((uint32_t)lr << 9) | (uint32_t)(c4 + j);
            }
        }
    }
    __syncthreads();

    const int n = (s_cnt < CAPS) ? s_cnt : CAPS;
    if (threadIdx.x == 0) *cnt_out = (uint32_t)n;
    for (int t = threadIdx.x; t < n; t += TPB) region[t] = surv[t];
}

__global__ __launch_bounds__(TPB) void stage1(const float* __restrict__ bmap,
                                              const float* __restrict__ pmap,
                                              uint32_t* __restrict__ bcnt,
                                              uint32_t* __restrict__ pcnt,
                                              uint32_t* __restrict__ blist,
                                              uint32_t* __restrict__ plist)
{
    __shared__ float df[(SR + 2) * WB];           // 19200 B (max of both maps)
    __shared__ uint32_t surv[CAPS];               // 3072 B
    const int b = blockIdx.y;
    if (blockIdx.x < NSB) {
        int s = blockIdx.x;
        stage1_impl<HB, WB>(bmap, s, b, bcnt + (size_t)b * NSB + s,
                            blist + ((size_t)b * NSB + s) * CAPS, df, surv);
    } else {
        int s = blockIdx.x - NSB;
        stage1_impl<HP, WP>(pmap, s, b, pcnt + (size_t)b * NSP + s,
                            plist + ((size_t)b * NSP + s) * CAPS, df, surv);
    }
}

// ---- stage 2: flat D16 radix-select -> exact-p rerank of <=256 -> decode ---
// 1 block/CU (128 blocks): LDS is free -> cache 16-bit keys for passes B/C.
template<int H, int W, int NS, bool BALL>
__device__ __forceinline__ void stage2_impl(const float* __restrict__ xmap,
                                            const float* __restrict__ pbbox,
                                            const uint32_t* __restrict__ cnt,
                                            const uint32_t* __restrict__ list,
                                            float* __restrict__ outp, int b,
                                            uint32_t* hist, uint64_t* outb,
                                            uint16_t* k16s, uint32_t* scnt)
{
    __shared__ int s_out;
    __shared__ uint32_t s_bin, s_ab, s_bin2, s_none;
    if (threadIdx.x == 0) { s_out = 0; s_none = 0; }
    if (threadIdx.x < NS) scnt[threadIdx.x] = cnt[threadIdx.x];
    if (threadIdx.x < 256) hist[threadIdx.x] = 0;
    __syncthreads();

    constexpr int TOT = NS * CAPS;

    // Pass A (flat, pipelined): cache key16 in LDS; histogram high byte.
    // Invalid slots -> k16 = 0 (impossible for finite D: flip(D)>>16 >= 0x80).
    for (int t = threadIdx.x; t < TOT; t += TPB) {
        int s = t / CAPS;                          // compile-time divisor
        int slot = t - s * CAPS;
        uint32_t rec = list[t];
        uint32_t k16 = (slot < (int)scnt[s]) ? (rec >> 12) : 0u;
        k16s[t] = (uint16_t)k16;
        if (k16) atomicAdd(&hist[k16 >> 8], 1u);
    }
    __syncthreads();
    suffix_scan_256(hist);
    if (threadIdx.x < 256) {
        uint32_t si = hist[threadIdx.x];
        uint32_t sn = (threadIdx.x < 255) ? hist[threadIdx.x + 1] : 0u;
        if (threadIdx.x == 0 && si < K1) s_none = 1;
        if (si >= K1 && sn < K1) { s_bin = threadIdx.x; s_ab = sn; }
    }
    __syncthreads();

    uint32_t T16 = 0;
    if (!s_none) {
        const uint32_t b3 = s_bin;
        const uint32_t k2 = K1 - s_ab;
        if (threadIdx.x < 256) hist[threadIdx.x] = 0;
        __syncthreads();
        // Pass B: LDS-only level-2 histogram among keys with high byte == b3.
        for (int t = threadIdx.x; t < TOT; t += TPB) {
            uint32_t k = k16s[t];
            if (k && (k >> 8) == b3) atomicAdd(&hist[k & 255u], 1u);
        }
        __syncthreads();
        suffix_scan_256(hist);
        if (threadIdx.x < 256) {
            uint32_t si = hist[threadIdx.x];
            uint32_t sn = (threadIdx.x < 255) ? hist[threadIdx.x + 1] : 0u;
            if (si >= k2 && sn < k2) s_bin2 = threadIdx.x;
        }
        __syncthreads();
        T16 = (b3 << 8) | s_bin2;
    }

    // Pass C: compact finalists (k16 >= T16, ties included); global re-read
    // + exact np p only for the ~256 winners.
    const float* x0 = xmap + (size_t)b * 2 * H * W;
    const float* x1 = x0 + (size_t)H * W;
    if (threadIdx.x < 256) outb[threadIdx.x] = 0;
    __syncthreads();
    for (int t = threadIdx.x; t < TOT; t += TPB) {
        uint32_t k = k16s[t];
        if (k && k >= T16) {
            int pos = atomicAdd(&s_out, 1);
            if (pos < 256) {
                uint32_t rec = list[t];
                int s = t / CAPS;                  // compile-time divisor
                int gidx = (s * SR + (int)((rec >> 9) & 7u)) * W + (int)(rec & 511u);
                float D = __fsub_rn(x1[gidx], x0[gidx]);
                float p = G_exact(D);
                outb[pos] = ((uint64_t)__float_as_uint(p) << 32) | (uint32_t)(~gidx);
            }
        }
    }
    __syncthreads();
    bitonic_sort_256(outb);

    // Decode top-100 (exact (p desc, idx asc) order).
    if (threadIdx.x < KTOP) {
        uint64_t k = outb[threadIdx.x];
        int id = (int)(~(uint32_t)k);
        float o0 = 0.f, o1 = 0.f, o2 = 0.f, o3 = 0.f, val = 0.f;
        if ((unsigned)id < (unsigned)(H * W)) {
            val = __uint_as_float((uint32_t)(k >> 32));
            int yy = id / W, xx = id - yy * W;     // compile-time divisor
            constexpr float ds = BALL ? 4.0f : 16.0f;
            float xc = (float)xx * ds + (ds - 1.0f) * 0.5f;
            float yc = (float)yy * ds + (ds - 1.0f) * 0.5f;
            float t0 = 0.f, t1 = 0.f;
            float t2 = BALL ? 40.0f : 0.0f, t3 = BALL ? 40.0f : 0.0f;
            if (!BALL) {
                const float* bb = pbbox + (size_t)b * 4 * H * W;
                constexpr float sx = (float)W * ds, sy = (float)H * ds;
                t0 = bb[id]             * sx;
                t1 = bb[id + H * W]     * sy;
                t2 = bb[id + 2 * H * W] * sx;
                t3 = bb[id + 3 * H * W] * sy;
            }
            float bx = xc + t0, by = yc + t1;
            o0 = bx - 0.5f * t2;
            o1 = by - 0.5f * t3;
            o2 = bx + 0.5f * t2;
            o3 = by + 0.5f * t3;
        }
        float* op = outp + (size_t)threadIdx.x * 5;
        op[0] = o0; op[1] = o1; op[2] = o2; op[3] = o3; op[4] = val;
    }
}

__global__ __launch_bounds__(TPB) void stage2(const float* __restrict__ bmap,
                                              const float* __restrict__ pmap,
                                              const float* __restrict__ pbbox,
                                              const uint32_t* __restrict__ bcnt,
                                              const uint32_t* __restrict__ pcnt,
                                              const uint32_t* __restrict__ blist,
                                              const uint32_t* __restrict__ plist,
                                              float* __restrict__ out)
{
    __shared__ uint32_t hist[256];
    __shared__ uint64_t outb[256];
    __shared__ uint16_t k16s[NSB * CAPS];          // 52224 B (ball worst case)
    __shared__ uint32_t scnt[NSB];
    if (blockIdx.x < NB) {
        int b = blockIdx.x;
        stage2_impl<HB, WB, NSB, true>(bmap, nullptr,
            bcnt + (size_t)b * NSB, blist + (size_t)b * NSB * CAPS,
            out + (size_t)NB * KTOP * 5 + (size_t)b * KTOP * 5, b,
            hist, outb, k16s, scnt);
    } else {
        int b = blockIdx.x - NB;
        stage2_impl<HP, WP, NSP, false>(pmap, pbbox,
            pcnt + (size_t)b * NSP, plist + (size_t)b * NSP * CAPS,
            out + (size_t)b * KTOP * 5, b, hist, outb, k16s, scnt);
    }
}

// ---- launch -----------------------------------------------------------------
extern "C" void kernel_launch(void* const* d_in, const int* in_sizes, int n_in,
                              void* d_out, int out_size, void* d_ws, size_t ws_size,
                              hipStream_t stream) {
    const float* pmap  = (const float*)d_in[0];   // [64,2,68,120]
    const float* pbbox = (const float*)d_in[1];   // [64,4,68,120]
    const float* bmap  = (const float*)d_in[2];   // [64,2,272,480]
    float* out = (float*)d_out;                   // player [64,100,5] then ball

    uint32_t* bcnt  = (uint32_t*)d_ws;                        // 64*34 u32
    uint32_t* pcnt  = bcnt + (size_t)NB * NSB;                // 64*9 u32
    uint32_t* blist = pcnt + (size_t)NB * NSP;                // 64*34*768 u32
    uint32_t* plist = blist + (size_t)NB * NSB * CAPS;        // 64*9*768 u32
    // ws usage: ~8.5 MB; counts written unconditionally each call (no init).

    stage1<<<dim3(NSB + NSP, NB), TPB, 0, stream>>>(bmap, pmap, bcnt, pcnt,
                                                    blist, plist);
    stage2<<<2 * NB, TPB, 0, stream>>>(bmap, pmap, pbbox, bcnt, pcnt,
                                       blist, plist, out);
}